// Round 4
// baseline (605.938 us; speedup 1.0000x reference)
//
#include <hip/hip_runtime.h>

// ============================================================================
// TypeNet triplet embedder: 2x(LSTM + BatchNorm) + FC + L2norm, for a,p,n.
// Round 4: 2-tile interleave + conflict-free A-layout LDS.
//  - 48 WGs x 512 thr; each WG runs TWO independent 16-row recurrences
//    (same input => shared Whh/W2s B-frags). Tile B's issue hides tile A's
//    latency (barrier skew, ds_read, MFMA dep chain, trans chain).
//  - h LDS buffers in MFMA A-fragment order: lane's 8 halves contiguous at
//    lane*16B => ds_read_b128 conflict-free. Writers: 4x b16 scatter.
//  - lstm1: x pre-converted to fp16 A-frag tensor (xpad, 3MB), depth-1 reg
//    prefetch; hs1 written via cooperative coalesced copy (float2/thread)
//    in A-frag order; lstm2 prefetches it as lane-contiguous dwordx4.
//  - BAR = s_waitcnt lgkmcnt(0) + s_barrier (no vmcnt drain; all cross-wave
//    traffic in the step loop is LDS).
// ============================================================================

typedef __attribute__((ext_vector_type(8))) _Float16 half8;
typedef __attribute__((ext_vector_type(4))) float f32x4;

#define TS 128
#define HID 128
#define NGATE 512
#define INV_N (1.0f/65536.0f)   // 1/(B*T)

#define BAR() asm volatile("s_waitcnt lgkmcnt(0)\n\ts_barrier" ::: "memory")

__device__ __forceinline__ float rcpf(float x) { return __builtin_amdgcn_rcpf(x); }
__device__ __forceinline__ float clamp20(float x) { return fminf(fmaxf(x, -20.0f), 20.0f); }

// Fused LSTM gate elementwise: returns h (fp16), updates c. 8 trans/elem.
__device__ __forceinline__ _Float16 lstm_cell(float zi, float zf, float zg, float zo,
                                              float& c) {
  zg = clamp20(zg);
  float ei = __expf(-zi);
  float eg = __expf(-2.0f * zg);
  float ef = __expf(-zf);
  float fv = rcpf(1.0f + ef);
  float ig = (1.0f - eg) * rcpf((1.0f + ei) * (1.0f + eg));  // sigmoid(zi)*tanh(zg)
  float cc = fv * c + ig;
  c = cc;
  float ccl = clamp20(cc);
  float eo = __expf(-zo);
  float ec = __expf(-2.0f * ccl);
  float hv = (1.0f - ec) * rcpf((1.0f + eo) * (1.0f + ec));  // sigmoid(zo)*tanh(cc)
  return (_Float16)hv;
}

// ---------------------------------------------------------------------------
__global__ void prep_whhT(const float* __restrict__ Whh1,
                          const float* __restrict__ Whh2,
                          _Float16* __restrict__ whhT1,
                          _Float16* __restrict__ whhT2) {
  int i = blockIdx.x * 256 + threadIdx.x;      // 512 blocks -> 131072
  int which = i >> 16, idx = i & 65535;
  int k = idx >> 9, g = idx & 511;
  const float* src = which ? Whh2 : Whh1;
  _Float16* dst = which ? whhT2 : whhT1;
  dst[idx] = (_Float16)src[g * HID + k];
}

__global__ void prep_bias(const float* __restrict__ bih1, const float* __restrict__ bhh1,
                          const float* __restrict__ bih2, const float* __restrict__ bhh2,
                          float* __restrict__ b1c, float* __restrict__ b2c) {
  int i = blockIdx.x * 256 + threadIdx.x;      // 4 blocks -> 1024
  if (i < 512) b1c[i] = bih1[i] + bhh1[i];
  else         b2c[i - 512] = bih2[i - 512] + bhh2[i - 512];
}

// x -> fp16 A-frag tensor: xpad[tile][t][16 r][8 d] (d>=5 zero). 3.1 MB.
__global__ void prep_xpad(const float* __restrict__ xa, const float* __restrict__ xp,
                          const float* __restrict__ xn, _Float16* __restrict__ xpad) {
  int i = blockIdx.x * 256 + threadIdx.x;      // 6144 blocks -> 1,572,864
  int tile = i >> 14, rem = i & 16383;
  int t = rem >> 7, r = (rem >> 3) & 15, d = i & 7;
  int inp = tile >> 5, rloc = (tile & 31) * 16;
  const float* x = (inp == 0) ? xa : ((inp == 1) ? xp : xn);
  xpad[i] = (d < 5) ? (_Float16)x[(rloc + r) * 640 + t * 5 + d] : (_Float16)0.0f;
}

// ---------------------------------------------------------------------------
// LSTM layer 1. 48 WGs, 2 tiles each. hs1: [96 tile][128 t][2048 halves]
// in A-frag order (lane-contiguous 16B blocks).
// ---------------------------------------------------------------------------
__global__ __launch_bounds__(512, 2) void lstm1_kernel(
    const _Float16* __restrict__ xpad,   // [96][128][16][8]
    const float* __restrict__ Wih1,      // [512][5]
    const float* __restrict__ b1c,       // [512]
    const _Float16* __restrict__ whhT,   // [128 k][512 g]
    _Float16* __restrict__ hs1,
    float* __restrict__ s1sum, float* __restrict__ s1sq) {
  const int wg = blockIdx.x;             // 0..47
  const int tA = wg * 2, tB = tA + 1;
  const int inp = tA >> 5;

  const int tid = threadIdx.x;
  const int w = tid >> 6;
  const int lane = tid & 63;
  const int l15 = lane & 15;
  const int quad = lane >> 4;
  const int col = w * 16 + l15;
  const int kb = quad * 8;

  __shared__ _Float16 hb[2][2][2048];    // [tile][buf][A-frag halves], 16 KB

  for (int i = tid; i < 2 * 2 * 2048; i += 512) ((_Float16*)hb)[i] = (_Float16)0.0f;

  // A-frag read base (halves): + kt*512
  const int rbase = (quad * 16 + l15) * 8;
  // writer slot (halves) for (row=quad*4+r, col): + r*8
  const int wslot = (w >> 1) * 512 + (((w & 1) * 2 + (l15 >> 3)) * 16 + quad * 4) * 8 + (l15 & 7);

  // Persistent B fragments
  half8 bh[4][4];                        // [kt][gate]
#pragma unroll
  for (int kt = 0; kt < 4; ++kt)
#pragma unroll
    for (int gt = 0; gt < 4; ++gt) {
      int gcol = gt * 128 + col;
      half8 v;
#pragma unroll
      for (int j = 0; j < 8; ++j) v[j] = whhT[(kt * 32 + kb + j) * NGATE + gcol];
      bh[kt][gt] = v;
    }
  half8 bx[4];                           // Wih1 K=32-padded (quad0, j<5)
#pragma unroll
  for (int gt = 0; gt < 4; ++gt) {
    half8 v = {0, 0, 0, 0, 0, 0, 0, 0};
    if (quad == 0) {
#pragma unroll
      for (int j = 0; j < 5; ++j) v[j] = (_Float16)Wih1[(gt * 128 + col) * 5 + j];
    }
    bx[gt] = v;
  }
  f32x4 biasv[4];
#pragma unroll
  for (int gt = 0; gt < 4; ++gt) {
    float b = b1c[gt * 128 + col];
    biasv[gt][0] = b; biasv[gt][1] = b; biasv[gt][2] = b; biasv[gt][3] = b;
  }

  // depth-1 x prefetch (quad0 lanes only; others stay zero)
  half8 xpA = {0,0,0,0,0,0,0,0}, xpB = {0,0,0,0,0,0,0,0};
  if (quad == 0) {
    xpA = *(const half8*)&xpad[((size_t)(tA * TS + 0) * 16 + l15) * 8];
    xpB = *(const half8*)&xpad[((size_t)(tB * TS + 0) * 16 + l15) * 8];
  }

  float cA[4] = {0,0,0,0}, cB[4] = {0,0,0,0};
  float ssum = 0.0f, ssq = 0.0f;

  __syncthreads();                       // hb zero-init visible

  for (int t = 0; t < TS; ++t) {
    // ---- pre-barrier: x-part, both tiles ----
    f32x4 aA[4], aB[4];
#pragma unroll
    for (int gt = 0; gt < 4; ++gt)
      aA[gt] = __builtin_amdgcn_mfma_f32_16x16x32_f16(xpA, bx[gt], biasv[gt], 0, 0, 0);
#pragma unroll
    for (int gt = 0; gt < 4; ++gt)
      aB[gt] = __builtin_amdgcn_mfma_f32_16x16x32_f16(xpB, bx[gt], biasv[gt], 0, 0, 0);
    if (t + 1 < TS && quad == 0) {       // prefetch next step's x A-frags
      xpA = *(const half8*)&xpad[((size_t)(tA * TS + t + 1) * 16 + l15) * 8];
      xpB = *(const half8*)&xpad[((size_t)(tB * TS + t + 1) * 16 + l15) * 8];
    }
    BAR();                               // h(t-1) LDS writes visible
    // ---- cooperative coalesced store of h(t-1) to hs1 (A-frag order) ----
    if (t > 0) {
      float2 cpA = *(const float2*)&hb[0][t & 1][tid * 4];
      float2 cpB = *(const float2*)&hb[1][t & 1][tid * 4];
      *(float2*)&hs1[((size_t)tA * TS + (t - 1)) * 2048 + tid * 4] = cpA;
      *(float2*)&hs1[((size_t)tB * TS + (t - 1)) * 2048 + tid * 4] = cpB;
    }
    // ---- h-part: conflict-free b128 reads, tight scope ----
#pragma unroll
    for (int kt = 0; kt < 4; ++kt) {
      half8 ahA = *(const half8*)&hb[0][t & 1][kt * 512 + rbase];
      half8 ahB = *(const half8*)&hb[1][t & 1][kt * 512 + rbase];
#pragma unroll
      for (int gt = 0; gt < 4; ++gt)
        aA[gt] = __builtin_amdgcn_mfma_f32_16x16x32_f16(ahA, bh[kt][gt], aA[gt], 0, 0, 0);
#pragma unroll
      for (int gt = 0; gt < 4; ++gt)
        aB[gt] = __builtin_amdgcn_mfma_f32_16x16x32_f16(ahB, bh[kt][gt], aB[gt], 0, 0, 0);
    }
    // ---- elementwise, both tiles ----
    const int wb = (t + 1) & 1;
#pragma unroll
    for (int r = 0; r < 4; ++r) {
      _Float16 hhA = lstm_cell(aA[0][r], aA[1][r], aA[2][r], aA[3][r], cA[r]);
      float hrA = (float)hhA;
      ssum += hrA; ssq += hrA * hrA;
      hb[0][wb][wslot + r * 8] = hhA;
      _Float16 hhB = lstm_cell(aB[0][r], aB[1][r], aB[2][r], aB[3][r], cB[r]);
      float hrB = (float)hhB;
      ssum += hrB; ssq += hrB * hrB;
      hb[1][wb][wslot + r * 8] = hhB;
    }
  }
  BAR();                                 // h(127) writes visible
  {
    float2 cpA = *(const float2*)&hb[0][0][tid * 4];
    float2 cpB = *(const float2*)&hb[1][0][tid * 4];
    *(float2*)&hs1[((size_t)tA * TS + (TS - 1)) * 2048 + tid * 4] = cpA;
    *(float2*)&hs1[((size_t)tB * TS + (TS - 1)) * 2048 + tid * 4] = cpB;
  }
  float s = ssum, q = ssq;
  s += __shfl_xor(s, 16); s += __shfl_xor(s, 32);
  q += __shfl_xor(q, 16); q += __shfl_xor(q, 32);
  if (quad == 0) {
    atomicAdd(&s1sum[inp * HID + col], s);
    atomicAdd(&s1sq[inp * HID + col], q);
  }
}

// ---------------------------------------------------------------------------
__global__ void finalize1_kernel(const float* __restrict__ s1sum, const float* __restrict__ s1sq,
                                 const float* __restrict__ g1, const float* __restrict__ b1,
                                 float* __restrict__ scale1, float* __restrict__ shift1) {
  int i = blockIdx.x * 128 + threadIdx.x;   // 3 blocks x 128
  int h = i & 127;
  float m = s1sum[i] * INV_N;
  float v = s1sq[i] * INV_N - m * m;
  float s = g1[h] * rsqrtf(v + 1e-5f);
  scale1[i] = s;
  shift1[i] = b1[h] - m * s;
}

__global__ void w2s_kernel(const float* __restrict__ scale1, const float* __restrict__ Wih2,
                           _Float16* __restrict__ w2s) {
  int i = blockIdx.x * 256 + threadIdx.x;   // 768 blocks -> [3][128 k][512 g]
  int inp = i >> 16, rem = i & 65535, k = rem >> 9, g = rem & 511;
  w2s[i] = (_Float16)(scale1[inp * HID + k] * Wih2[g * HID + k]);
}

__global__ void bias2_kernel(const float* __restrict__ shift1, const float* __restrict__ Wih2,
                             const float* __restrict__ b2c, float* __restrict__ bias2eff) {
  int i = blockIdx.x * 512 + threadIdx.x;   // 3 blocks x 512
  int inp = i >> 9, g = i & 511;
  float acc = b2c[g];
  for (int h = 0; h < HID; ++h) acc += shift1[inp * HID + h] * Wih2[g * HID + h];
  bias2eff[i] = acc;
}

// ---------------------------------------------------------------------------
// LSTM layer 2: fused (folded-BN1) input GEMM + recurrence, 2 tiles/WG.
// ---------------------------------------------------------------------------
__global__ __launch_bounds__(512, 2) void lstm2_kernel(
    const _Float16* __restrict__ hs1,    // [96][128][2048] A-frag order
    const _Float16* __restrict__ whhT2,  // [128 k][512 g]
    const _Float16* __restrict__ w2s,    // [3][128 k][512 g]
    const float* __restrict__ bias2eff,  // [3][512]
    _Float16* __restrict__ h_last,       // [1536][128]
    float* __restrict__ s2sum, float* __restrict__ s2sq) {
  const int wg = blockIdx.x;             // 0..47
  const int tA = wg * 2, tB = tA + 1;
  const int inp = tA >> 5;
  const int gr0A = tA * 16, gr0B = tB * 16;

  const int tid = threadIdx.x;
  const int w = tid >> 6;
  const int lane = tid & 63;
  const int l15 = lane & 15;
  const int quad = lane >> 4;
  const int col = w * 16 + l15;
  const int kb = quad * 8;

  __shared__ _Float16 hb[2][2][2048];    // 16 KB
  for (int i = tid; i < 2 * 2 * 2048; i += 512) ((_Float16*)hb)[i] = (_Float16)0.0f;

  const int rbase = (quad * 16 + l15) * 8;
  const int wslot = (w >> 1) * 512 + (((w & 1) * 2 + (l15 >> 3)) * 16 + quad * 4) * 8 + (l15 & 7);

  const _Float16* w2sI = w2s + (size_t)inp * HID * NGATE;
  half8 bh[4][4], bxw[4][4];
#pragma unroll
  for (int kt = 0; kt < 4; ++kt)
#pragma unroll
    for (int gt = 0; gt < 4; ++gt) {
      int gcol = gt * 128 + col;
      half8 vh, vx;
#pragma unroll
      for (int j = 0; j < 8; ++j) {
        vh[j] = whhT2[(kt * 32 + kb + j) * NGATE + gcol];
        vx[j] = w2sI[(kt * 32 + kb + j) * NGATE + gcol];
      }
      bh[kt][gt] = vh;
      bxw[kt][gt] = vx;
    }
  f32x4 biasv[4];
#pragma unroll
  for (int gt = 0; gt < 4; ++gt) {
    float b = bias2eff[inp * NGATE + gt * 128 + col];
    biasv[gt][0] = b; biasv[gt][1] = b; biasv[gt][2] = b; biasv[gt][3] = b;
  }

  const _Float16* hgA = hs1 + (size_t)tA * TS * 2048;
  const _Float16* hgB = hs1 + (size_t)tB * TS * 2048;
  half8 xpA[4], xpB[4];                  // depth-1 prefetch of layer-1 A-frags
#pragma unroll
  for (int kt = 0; kt < 4; ++kt) {
    xpA[kt] = *(const half8*)&hgA[kt * 512 + rbase];
    xpB[kt] = *(const half8*)&hgB[kt * 512 + rbase];
  }

  float cA[4] = {0,0,0,0}, cB[4] = {0,0,0,0};
  float ssum = 0.0f, ssq = 0.0f;

  __syncthreads();                       // hb zero-init visible

  for (int t = 0; t < TS; ++t) {
    // ---- pre-barrier: input-GEMM part from prefetched regs ----
    f32x4 aA[4], aB[4];
#pragma unroll
    for (int gt = 0; gt < 4; ++gt)
      aA[gt] = __builtin_amdgcn_mfma_f32_16x16x32_f16(xpA[0], bxw[0][gt], biasv[gt], 0, 0, 0);
#pragma unroll
    for (int gt = 0; gt < 4; ++gt)
      aB[gt] = __builtin_amdgcn_mfma_f32_16x16x32_f16(xpB[0], bxw[0][gt], biasv[gt], 0, 0, 0);
#pragma unroll
    for (int kt = 1; kt < 4; ++kt) {
#pragma unroll
      for (int gt = 0; gt < 4; ++gt)
        aA[gt] = __builtin_amdgcn_mfma_f32_16x16x32_f16(xpA[kt], bxw[kt][gt], aA[gt], 0, 0, 0);
#pragma unroll
      for (int gt = 0; gt < 4; ++gt)
        aB[gt] = __builtin_amdgcn_mfma_f32_16x16x32_f16(xpB[kt], bxw[kt][gt], aB[gt], 0, 0, 0);
    }
    if (t + 1 < TS) {                    // prefetch next step's layer-1 tiles
#pragma unroll
      for (int kt = 0; kt < 4; ++kt) {
        xpA[kt] = *(const half8*)&hgA[(size_t)(t + 1) * 2048 + kt * 512 + rbase];
        xpB[kt] = *(const half8*)&hgB[(size_t)(t + 1) * 2048 + kt * 512 + rbase];
      }
    }
    BAR();                               // h(t-1) LDS writes visible
#pragma unroll
    for (int kt = 0; kt < 4; ++kt) {
      half8 ahA = *(const half8*)&hb[0][t & 1][kt * 512 + rbase];
      half8 ahB = *(const half8*)&hb[1][t & 1][kt * 512 + rbase];
#pragma unroll
      for (int gt = 0; gt < 4; ++gt)
        aA[gt] = __builtin_amdgcn_mfma_f32_16x16x32_f16(ahA, bh[kt][gt], aA[gt], 0, 0, 0);
#pragma unroll
      for (int gt = 0; gt < 4; ++gt)
        aB[gt] = __builtin_amdgcn_mfma_f32_16x16x32_f16(ahB, bh[kt][gt], aB[gt], 0, 0, 0);
    }
    const int wb = (t + 1) & 1;
#pragma unroll
    for (int r = 0; r < 4; ++r) {
      _Float16 hhA = lstm_cell(aA[0][r], aA[1][r], aA[2][r], aA[3][r], cA[r]);
      float hrA = (float)hhA;
      ssum += hrA; ssq += hrA * hrA;
      hb[0][wb][wslot + r * 8] = hhA;
      _Float16 hhB = lstm_cell(aB[0][r], aB[1][r], aB[2][r], aB[3][r], cB[r]);
      float hrB = (float)hhB;
      ssum += hrB; ssq += hrB * hrB;
      hb[1][wb][wslot + r * 8] = hhB;
      if (t == TS - 1) {
        int row = quad * 4 + r;
        h_last[(size_t)(gr0A + row) * HID + col] = hhA;
        h_last[(size_t)(gr0B + row) * HID + col] = hhB;
      }
    }
  }

  float s = ssum, q = ssq;
  s += __shfl_xor(s, 16); s += __shfl_xor(s, 32);
  q += __shfl_xor(q, 16); q += __shfl_xor(q, 32);
  if (quad == 0) {
    atomicAdd(&s2sum[inp * HID + col], s);
    atomicAdd(&s2sq[inp * HID + col], q);
  }
}

// ---------------------------------------------------------------------------
// Head: BN2 finalize + FC + L2 normalize. 96 WGs x 16 rows.
// ---------------------------------------------------------------------------
__global__ __launch_bounds__(256, 1) void head_kernel(
    const _Float16* __restrict__ h_last,
    const float* __restrict__ s2sum, const float* __restrict__ s2sq,
    const float* __restrict__ g2, const float* __restrict__ b2,
    const float* __restrict__ fcW, const float* __restrict__ fcb,
    float* __restrict__ out) {
  const int wg = blockIdx.x;
  const int inp = wg >> 5;
  const int gr0 = wg * 16;
  const int tid = threadIdx.x;

  __shared__ float fcwT[128][132];       // fcwT[h][j] = fcW[j][h]
  __shared__ float bnh[16][132];
  __shared__ float s2[128], sh2[128];
  __shared__ float part[16][16];
  __shared__ float inv[16];

  if (tid < 128) {
    float m = s2sum[inp * HID + tid] * INV_N;
    float v = s2sq[inp * HID + tid] * INV_N - m * m;
    float s = g2[tid] * rsqrtf(v + 1e-5f);
    s2[tid] = s; sh2[tid] = b2[tid] - m * s;
  }
  for (int i = tid; i < 16384; i += 256) {
    int j = i >> 7, h = i & 127;
    fcwT[h][j] = fcW[i];
  }
  __syncthreads();
  {
    int row = tid >> 4, c0 = (tid & 15) * 8;
#pragma unroll
    for (int k = 0; k < 8; ++k) {
      int h = c0 + k;
      bnh[row][h] = (float)h_last[(gr0 + row) * HID + h] * s2[h] + sh2[h];
    }
  }
  __syncthreads();
  const int row = tid >> 4, jl = tid & 15;
  float emb[8];
  float sq = 0.0f;
#pragma unroll
  for (int jj = 0; jj < 8; ++jj) {
    int j = jl + jj * 16;
    float acc = fcb[j];
    for (int h = 0; h < HID; ++h) acc += bnh[row][h] * fcwT[h][j];
    emb[jj] = acc; sq += acc * acc;
  }
  part[row][jl] = sq;
  __syncthreads();
  if (tid < 16) {
    float s = 0.0f;
    for (int k = 0; k < 16; ++k) s += part[tid][k];
    float nrm = sqrtf(s);
    inv[tid] = 1.0f / fmaxf(nrm, 1e-12f);
  }
  __syncthreads();
#pragma unroll
  for (int jj = 0; jj < 8; ++jj)
    out[(gr0 + row) * HID + jl + jj * 16] = emb[jj] * inv[row];
}

// ---------------------------------------------------------------------------
extern "C" void kernel_launch(void* const* d_in, const int* in_sizes, int n_in,
                              void* d_out, int out_size, void* d_ws, size_t ws_size,
                              hipStream_t stream) {
  const float* a    = (const float*)d_in[0];
  const float* p    = (const float*)d_in[1];
  const float* nn   = (const float*)d_in[2];
  const float* Wih1 = (const float*)d_in[3];
  const float* Whh1 = (const float*)d_in[4];
  const float* bih1 = (const float*)d_in[5];
  const float* bhh1 = (const float*)d_in[6];
  const float* g1   = (const float*)d_in[7];
  const float* b1   = (const float*)d_in[8];
  const float* Wih2 = (const float*)d_in[9];
  const float* Whh2 = (const float*)d_in[10];
  const float* bih2 = (const float*)d_in[11];
  const float* bhh2 = (const float*)d_in[12];
  const float* g2   = (const float*)d_in[13];
  const float* b2   = (const float*)d_in[14];
  const float* fcW  = (const float*)d_in[15];
  const float* fcb  = (const float*)d_in[16];

  char* ws = (char*)d_ws;
  float* s1sum = (float*)(ws + 0);           // 384
  float* s1sq  = s1sum + 384;
  float* s2sum = s1sum + 768;
  float* s2sq  = s1sum + 1152;               // stats end @6144B
  float* b1c   = (float*)(ws + 6144);        // 512
  float* b2c   = b1c + 512;                  // ends @10240B
  float* scale1 = (float*)(ws + 10240);      // 384
  float* shift1 = scale1 + 384;              // ends @13312B
  float* bias2eff = (float*)(ws + 13312);    // 1536 -> ends @19456B
  _Float16* whhT1 = (_Float16*)(ws + 19456);   // 131072 -> @150528
  _Float16* whhT2 = (_Float16*)(ws + 150528);  // 131072 -> @281600
  _Float16* w2s   = (_Float16*)(ws + 281600);  // 393216 -> @674816
  _Float16* hlast = (_Float16*)(ws + 674816);  // 393216 -> @1068032
  _Float16* xpad  = (_Float16*)(ws + 1068032); // 3145728 -> @4213760
  _Float16* hs1   = (_Float16*)(ws + 4213760); // 50331648 -> ~54.5MB total

  hipMemsetAsync(ws, 0, 6144, stream);  // zero BN stats accumulators

  prep_whhT<<<512, 256, 0, stream>>>(Whh1, Whh2, whhT1, whhT2);
  prep_bias<<<4, 256, 0, stream>>>(bih1, bhh1, bih2, bhh2, b1c, b2c);
  prep_xpad<<<6144, 256, 0, stream>>>(a, p, nn, xpad);
  lstm1_kernel<<<48, 512, 0, stream>>>(xpad, Wih1, b1c, whhT1, hs1, s1sum, s1sq);
  finalize1_kernel<<<3, 128, 0, stream>>>(s1sum, s1sq, g1, b1, scale1, shift1);
  w2s_kernel<<<768, 256, 0, stream>>>(scale1, Wih2, w2s);
  bias2_kernel<<<3, 512, 0, stream>>>(shift1, Wih2, b2c, bias2eff);
  lstm2_kernel<<<48, 512, 0, stream>>>(hs1, whhT2, w2s, bias2eff, hlast, s2sum, s2sq);
  head_kernel<<<96, 256, 0, stream>>>(hlast, s2sum, s2sq, g2, b2, fcW, fcb, (float*)d_out);
}